// Round 6
// baseline (388.528 us; speedup 1.0000x reference)
//
#include <hip/hip_runtime.h>
#include <hip/hip_fp16.h>

#define U_DIM 400
#define V_DIM 400
#define TEXELS (U_DIM * V_DIM)

#define IBSHIFT 3
#define IBANDS ((U_DIM + (1 << IBSHIFT) - 1) >> IBSHIFT)   // 50
#define MAXKEYS 256            // M * IBANDS must fit
#define NREP 64                // cursor replicas per key

#define SC_THREADS 512
#define SC_PPT 4
#define SC_PTS (SC_THREADS * SC_PPT)   // 2048 points staged per block

typedef unsigned long long u64;

__device__ __forceinline__ void uv_to_coords(float uu, float vv,
                                             float& iu, float& jv) {
  iu = uu * (float)U_DIM; if (iu >= (float)U_DIM) iu = (float)(U_DIM - 1);
  jv = vv * (float)V_DIM; if (jv >= (float)V_DIM) jv = (float)(V_DIM - 1);
}

__device__ __forceinline__ void corner_setup(float iu, float jv,
                                             float* w, int* t) {
  float i1f = floorf(iu), j1f = floorf(jv);
  int i1 = (int)i1f, j1 = (int)j1f;
  int i2 = i1 + 1; if (i2 == U_DIM) i2 = 0;
  int j2 = j1 + 1; if (j2 == V_DIM) j2 = 0;
  float ir = iu - i1f, jr = jv - j1f;
  w[0] = (1.0f - ir) * (1.0f - jr);
  w[1] = ir * (1.0f - jr);
  w[2] = (1.0f - ir) * jr;
  w[3] = ir * jr;
  t[0] = i1 * V_DIM + j1;
  t[1] = i2 * V_DIM + j1;
  t[2] = i1 * V_DIM + j2;
  t[3] = i2 * V_DIM + j2;
}

// ---------------- pipeline kernels ----------------

__global__ __launch_bounds__(256) void zero_kernel(unsigned* __restrict__ p, int n) {
  int i = blockIdx.x * blockDim.x + threadIdx.x;
  if (i < n) p[i] = 0u;
}

// fp16 split repack: tbl0 = 16B/texel (W[0..7]), tbl1 = 8B/texel (W[8],b0,b1,b2)
__global__ __launch_bounds__(256) void repack_split_kernel(
    const float* __restrict__ mp, const float* __restrict__ bp,
    u64* __restrict__ tbl0, u64* __restrict__ tbl1, int total_texels) {
  int t = blockIdx.x * blockDim.x + threadIdx.x;
  if (t >= total_texels) return;
  const float* pw = mp + (size_t)t * 9;
  const float* pb = bp + (size_t)t * 3;
  union { __half h[12]; u64 q[3]; } u;
#pragma unroll
  for (int k = 0; k < 8; ++k) u.h[k] = __float2half(pw[k]);
  u.h[8]  = __float2half(pw[8]);
  u.h[9]  = __float2half(pb[0]);
  u.h[10] = __float2half(pb[1]);
  u.h[11] = __float2half(pb[2]);
  tbl0[(size_t)t * 2 + 0] = u.q[0];
  tbl0[(size_t)t * 2 + 1] = u.q[1];
  tbl1[t] = u.q[2];
}

// per-block LDS histogram of (m, i-band) keys -> <=256 replicated atomics/block
__global__ __launch_bounds__(SC_THREADS) void hist_band_kernel(
    const int* __restrict__ m, const float* __restrict__ u,
    unsigned* __restrict__ hist, int N) {
  __shared__ unsigned c[MAXKEYS];
  int tid = threadIdx.x;
  if (tid < MAXKEYS) c[tid] = 0u;
  __syncthreads();
  int base = blockIdx.x * SC_PTS;
  unsigned rep = (unsigned)blockIdx.x & (NREP - 1);
#pragma unroll
  for (int k = 0; k < SC_PPT; ++k) {
    int n = base + k * SC_THREADS + tid;
    if (n < N) {
      int mm = __builtin_nontemporal_load(&m[n]);
      float uu = __builtin_nontemporal_load(&u[n]);
      float iu = uu * (float)U_DIM;
      if (iu >= (float)U_DIM) iu = (float)(U_DIM - 1);
      int i1 = (int)floorf(iu);
      int key = mm * IBANDS + (i1 >> IBSHIFT);
      atomicAdd(&c[key], 1u);
    }
  }
  __syncthreads();
  if (tid < MAXKEYS && c[tid])
    atomicAdd(&hist[tid * NREP + rep], c[tid]);
}

#define SCAN_THREADS 1024
// single-workgroup exclusive scan (key-major over key*NREP+rep)
__global__ __launch_bounds__(SCAN_THREADS) void scan_kernel(
    const unsigned* __restrict__ hist, unsigned* __restrict__ cursor, int nb) {
  __shared__ unsigned buf[2][SCAN_THREADS];
  __shared__ unsigned carry_s;
  if (threadIdx.x == 0) carry_s = 0u;
  __syncthreads();
  for (int base = 0; base < nb; base += SCAN_THREADS) {
    int i = base + threadIdx.x;
    unsigned vv = (i < nb) ? hist[i] : 0u;
    int src = 0;
    buf[0][threadIdx.x] = vv;
    __syncthreads();
    for (int off = 1; off < SCAN_THREADS; off <<= 1) {
      unsigned t = buf[src][threadIdx.x];
      if ((int)threadIdx.x >= off) t += buf[src][threadIdx.x - off];
      buf[1 - src][threadIdx.x] = t;
      src = 1 - src;
      __syncthreads();
    }
    unsigned incl = buf[src][threadIdx.x];
    unsigned excl = incl - vv + carry_s;
    if (i < nb) cursor[i] = excl;
    __syncthreads();
    if (threadIdx.x == SCAN_THREADS - 1) carry_s += incl;
    __syncthreads();
  }
}

// scatter: stage 2048 points in LDS grouped by (m,i-band); claim contiguous
// global runs from replicated cursors; flush 24B recs {x0,x1,x2,iu,jv,m} with
// ~10-record runs (coalesced); inv[n]=slot written coalesced.
__global__ __launch_bounds__(SC_THREADS) void scatter_band_kernel(
    const float* __restrict__ x, const int* __restrict__ m,
    const float* __restrict__ u, const float* __restrict__ v,
    unsigned* __restrict__ cursor, u64* __restrict__ sorted,
    unsigned* __restrict__ inv, int N) {
  __shared__ float lrec[SC_PTS * 6];                 // 48 KB
  __shared__ unsigned short lkey[SC_PTS];            // 4 KB
  __shared__ unsigned cnt[MAXKEYS], startk[MAXKEYS], gbase[MAXKEYS];
  __shared__ unsigned sbuf[MAXKEYS];

  int tid = threadIdx.x;
  int base = blockIdx.x * SC_PTS;
  unsigned rep = (unsigned)blockIdx.x & (NREP - 1);

  if (tid < MAXKEYS) cnt[tid] = 0u;
  __syncthreads();

  float rec[SC_PPT][6];
  int key[SC_PPT];
  unsigned rank[SC_PPT];
  bool val[SC_PPT];
#pragma unroll
  for (int k = 0; k < SC_PPT; ++k) {
    int n = base + k * SC_THREADS + tid;
    val[k] = (n < N);
    key[k] = 0; rank[k] = 0;
    if (val[k]) {
      int mm = __builtin_nontemporal_load(&m[n]);
      float uu = __builtin_nontemporal_load(&u[n]);
      float vv = __builtin_nontemporal_load(&v[n]);
      float iu, jv;
      uv_to_coords(uu, vv, iu, jv);
      rec[k][0] = __builtin_nontemporal_load(&x[3 * n + 0]);
      rec[k][1] = __builtin_nontemporal_load(&x[3 * n + 1]);
      rec[k][2] = __builtin_nontemporal_load(&x[3 * n + 2]);
      rec[k][3] = iu;
      rec[k][4] = jv;
      rec[k][5] = __uint_as_float((unsigned)mm);
      int i1 = (int)floorf(iu);
      key[k] = mm * IBANDS + (i1 >> IBSHIFT);
      rank[k] = atomicAdd(&cnt[key[k]], 1u);
    }
  }
  __syncthreads();

  // exclusive scan of cnt[0..MAXKEYS) (first 256 threads, Hillis-Steele)
  {
    unsigned s0 = (tid < MAXKEYS) ? cnt[tid] : 0u;
    if (tid < MAXKEYS) sbuf[tid] = s0;
    __syncthreads();
    unsigned incl = s0;
    for (int off = 1; off < MAXKEYS; off <<= 1) {
      unsigned add = 0u;
      if (tid < MAXKEYS && tid >= off) add = sbuf[tid - off];
      __syncthreads();
      if (tid < MAXKEYS) { incl += add; sbuf[tid] = incl; }
      __syncthreads();
    }
    if (tid < MAXKEYS) startk[tid] = incl - s0;
  }
  // claim global runs
  if (tid < MAXKEYS && cnt[tid])
    gbase[tid] = atomicAdd(&cursor[tid * NREP + rep], cnt[tid]);
  __syncthreads();

  // place records into LDS at grouped positions; write inv coalesced
#pragma unroll
  for (int k = 0; k < SC_PPT; ++k) {
    if (val[k]) {
      unsigned pos = startk[key[k]] + rank[k];
      lkey[pos] = (unsigned short)key[k];
#pragma unroll
      for (int c = 0; c < 6; ++c) lrec[pos * 6 + c] = rec[k][c];
      int n = base + k * SC_THREADS + tid;
      inv[n] = gbase[key[k]] + rank[k];
    }
  }
  __syncthreads();

  // flush grouped runs to global
  int total = N - base; if (total > SC_PTS) total = SC_PTS;
  for (int pos = tid; pos < total; pos += SC_THREADS) {
    unsigned kk = lkey[pos];
    size_t slot = (size_t)gbase[kk] + (unsigned)pos - startk[kk];
    u64* d = sorted + slot * 3;
    const u64* s = (const u64*)&lrec[pos * 6];
    d[0] = s[0]; d[1] = s[1]; d[2] = s[2];
  }
}

// gather: sorted stream is (m,i-band)-contiguous -> table slice (77 KB) is
// L1/L2 resident. Result written IN PLACE over first 12B of the record.
__global__ __launch_bounds__(256) void gather_inplace_kernel(
    u64* __restrict__ sorted, const u64* __restrict__ tbl0,
    const u64* __restrict__ tbl1, int N) {
  int n = blockIdx.x * blockDim.x + threadIdx.x;
  if (n >= N) return;
  u64* rp = sorted + (size_t)n * 3;
  u64 r0 = rp[0];
  u64 r1 = rp[1];
  u64 r2 = rp[2];
  float x0 = __uint_as_float((unsigned)(r0 & 0xFFFFFFFFu));
  float x1 = __uint_as_float((unsigned)(r0 >> 32));
  float x2 = __uint_as_float((unsigned)(r1 & 0xFFFFFFFFu));
  float iu = __uint_as_float((unsigned)(r1 >> 32));
  float jv = __uint_as_float((unsigned)(r2 & 0xFFFFFFFFu));
  unsigned mm = (unsigned)(r2 >> 32);

  float w[4]; int t[4];
  corner_setup(iu, jv, w, t);
  const u64* b0 = tbl0 + (size_t)mm * ((size_t)TEXELS * 2);
  const u64* b1 = tbl1 + (size_t)mm * (size_t)TEXELS;

  float acc[12];
#pragma unroll
  for (int c = 0; c < 12; ++c) acc[c] = 0.0f;
#pragma unroll
  for (int c = 0; c < 4; ++c) {
    const u64* p0 = b0 + (size_t)t[c] * 2;
    u64 qa = p0[0], qb = p0[1];
    u64 qc = b1[t[c]];
    float wc = w[c];
    float2 f;
    unsigned h;
    h = (unsigned)(qa & 0xFFFFFFFFu);  f = __half22float2(*(const __half2*)&h);
    acc[0] = fmaf(wc, f.x, acc[0]);  acc[1] = fmaf(wc, f.y, acc[1]);
    h = (unsigned)(qa >> 32);          f = __half22float2(*(const __half2*)&h);
    acc[2] = fmaf(wc, f.x, acc[2]);  acc[3] = fmaf(wc, f.y, acc[3]);
    h = (unsigned)(qb & 0xFFFFFFFFu);  f = __half22float2(*(const __half2*)&h);
    acc[4] = fmaf(wc, f.x, acc[4]);  acc[5] = fmaf(wc, f.y, acc[5]);
    h = (unsigned)(qb >> 32);          f = __half22float2(*(const __half2*)&h);
    acc[6] = fmaf(wc, f.x, acc[6]);  acc[7] = fmaf(wc, f.y, acc[7]);
    h = (unsigned)(qc & 0xFFFFFFFFu);  f = __half22float2(*(const __half2*)&h);
    acc[8] = fmaf(wc, f.x, acc[8]);  acc[9] = fmaf(wc, f.y, acc[9]);
    h = (unsigned)(qc >> 32);          f = __half22float2(*(const __half2*)&h);
    acc[10] = fmaf(wc, f.x, acc[10]); acc[11] = fmaf(wc, f.y, acc[11]);
  }

  float o0 = fmaf(x0, acc[0], fmaf(x1, acc[3], fmaf(x2, acc[6], acc[9])));
  float o1 = fmaf(x0, acc[1], fmaf(x1, acc[4], fmaf(x2, acc[7], acc[10])));
  float o2 = fmaf(x0, acc[2], fmaf(x1, acc[5], fmaf(x2, acc[8], acc[11])));
  u64 lo = (u64)__float_as_uint(o0) | ((u64)__float_as_uint(o1) << 32);
  rp[0] = lo;
  ((unsigned*)rp)[2] = __float_as_uint(o2);
}

// unsort: out[3n] = result at sorted[inv[n]] (monotonic runs -> coalesced)
__global__ __launch_bounds__(256) void unsort_kernel(
    const unsigned* __restrict__ inv, const u64* __restrict__ sorted,
    float* __restrict__ out, int N) {
  int n = blockIdx.x * blockDim.x + threadIdx.x;
  if (n >= N) return;
  unsigned slot = __builtin_nontemporal_load(&inv[n]);
  const u64* p = sorted + (size_t)slot * 3;
  u64 lo = p[0];
  unsigned o2 = ((const unsigned*)p)[2];
  __builtin_nontemporal_store(__uint_as_float((unsigned)(lo & 0xFFFFFFFFu)), &out[3 * n + 0]);
  __builtin_nontemporal_store(__uint_as_float((unsigned)(lo >> 32)), &out[3 * n + 1]);
  __builtin_nontemporal_store(__uint_as_float(o2), &out[3 * n + 2]);
}

// ---------------- low-workspace fallback ----------------

__global__ __launch_bounds__(256) void interp_direct_kernel(
    const float* __restrict__ x, const int* __restrict__ mat,
    const float* __restrict__ u, const float* __restrict__ v,
    const float* __restrict__ mp, const float* __restrict__ bp,
    float* __restrict__ out, int N) {
  int n = blockIdx.x * blockDim.x + threadIdx.x;
  if (n >= N) return;
  float iu, jv;
  uv_to_coords(u[n], v[n], iu, jv);
  float w[4]; int t[4];
  corner_setup(iu, jv, w, t);
  size_t mb = (size_t)mat[n] * TEXELS;
  float acc[12];
#pragma unroll
  for (int c = 0; c < 12; ++c) acc[c] = 0.0f;
#pragma unroll
  for (int c = 0; c < 4; ++c) {
    const float* pm = mp + (mb + t[c]) * 9;
    const float* pb = bp + (mb + t[c]) * 3;
    float wc = w[c];
#pragma unroll
    for (int k = 0; k < 9; ++k) acc[k] = fmaf(wc, pm[k], acc[k]);
#pragma unroll
    for (int k = 0; k < 3; ++k) acc[9 + k] = fmaf(wc, pb[k], acc[9 + k]);
  }
  float x0 = x[3 * n], x1 = x[3 * n + 1], x2 = x[3 * n + 2];
  float o0 = fmaf(x0, acc[0], fmaf(x1, acc[3], fmaf(x2, acc[6], acc[9])));
  float o1 = fmaf(x0, acc[1], fmaf(x1, acc[4], fmaf(x2, acc[7], acc[10])));
  float o2 = fmaf(x0, acc[2], fmaf(x1, acc[5], fmaf(x2, acc[8], acc[11])));
  out[3 * n + 0] = o0;
  out[3 * n + 1] = o1;
  out[3 * n + 2] = o2;
}

// ---------------- launch ----------------

static inline size_t align_up(size_t v, size_t a) { return (v + a - 1) & ~(a - 1); }

extern "C" void kernel_launch(void* const* d_in, const int* in_sizes, int n_in,
                              void* d_out, int out_size, void* d_ws, size_t ws_size,
                              hipStream_t stream) {
  const float* x  = (const float*)d_in[0];
  const int*   m  = (const int*)d_in[1];
  const float* u  = (const float*)d_in[2];
  const float* v  = (const float*)d_in[3];
  const float* mp = (const float*)d_in[4];
  const float* bp = (const float*)d_in[5];
  float* out = (float*)d_out;

  int N = in_sizes[1];
  int M = in_sizes[4] / (TEXELS * 9);

  const int B = 256;
  int nblk  = (N + B - 1) / B;
  int nblk2 = (N + SC_PTS - 1) / SC_PTS;
  int nkeys = M * IBANDS;
  int nctl  = nkeys * NREP;

  size_t tbl0_bytes = (size_t)M * TEXELS * 16;
  size_t tbl1_bytes = (size_t)M * TEXELS * 8;
  size_t ctl_bytes  = (size_t)nctl * sizeof(unsigned);
  size_t sort_bytes = (size_t)N * 24;
  size_t inv_bytes  = (size_t)N * sizeof(unsigned);

  size_t off_tbl0 = 0;
  size_t off_tbl1 = align_up(off_tbl0 + tbl0_bytes, 256);
  size_t off_hist = align_up(off_tbl1 + tbl1_bytes, 256);
  size_t off_curs = align_up(off_hist + ctl_bytes, 256);
  size_t off_sort = align_up(off_curs + ctl_bytes, 256);
  size_t off_inv  = align_up(off_sort + sort_bytes, 256);
  size_t need     = off_inv + inv_bytes;

  bool ok = (nkeys <= MAXKEYS) && (N <= (1 << 30)) && (ws_size >= need);
  char* basep = (char*)d_ws;

  if (ok) {
    u64*      tbl0   = (u64*)(basep + off_tbl0);
    u64*      tbl1   = (u64*)(basep + off_tbl1);
    unsigned* hist   = (unsigned*)(basep + off_hist);
    unsigned* cursor = (unsigned*)(basep + off_curs);
    u64*      sorted = (u64*)(basep + off_sort);
    unsigned* inv    = (unsigned*)(basep + off_inv);

    zero_kernel<<<(nctl + B - 1) / B, B, 0, stream>>>(hist, nctl);
    int total_texels = M * TEXELS;
    repack_split_kernel<<<(total_texels + B - 1) / B, B, 0, stream>>>(
        mp, bp, tbl0, tbl1, total_texels);
    hist_band_kernel<<<nblk2, SC_THREADS, 0, stream>>>(m, u, hist, N);
    scan_kernel<<<1, SCAN_THREADS, 0, stream>>>(hist, cursor, nctl);
    scatter_band_kernel<<<nblk2, SC_THREADS, 0, stream>>>(
        x, m, u, v, cursor, sorted, inv, N);
    gather_inplace_kernel<<<nblk, B, 0, stream>>>(sorted, tbl0, tbl1, N);
    unsort_kernel<<<nblk, B, 0, stream>>>(inv, sorted, out, N);
  } else {
    interp_direct_kernel<<<nblk, B, 0, stream>>>(x, m, u, v, mp, bp, out, N);
  }
}